// Round 5
// baseline (156.126 us; speedup 1.0000x reference)
//
#include <hip/hip_runtime.h>

// FeatureWithRelativePosition: fused pairwise-dist -> Linear(4096->64) -> LN -> SiLU
// BS=4, N=4096, FEAT=64. fp32 in/out, bf16 MFMA inner product, fp32 accumulate.
//
// R8: ZERO in-loop barriers at FULL occupancy (R5's structure, R7's occupancy).
//     R7 post-mortem: counted-vmcnt barrier was neutral -> the stall is phase
//     lockstep (all 16 waves burst LDS together, then all compute together),
//     not the barrier drain. Fix: remove in-loop barriers entirely.
//     - 16 waves/block (1024 thr, 4 waves/SIMD). wave = (rs, ksl) as R7.
//     - W: wave-PRIVATE global_load_lds DMA, 4 KiB slice/chunk, double-
//       buffered (Wpriv[2][16][256] = 128 KiB). rs-pairs duplicate the slice
//       (2x DMA traffic, off critical path). Sync = wave-local vmcnt(6).
//     - pos: NO LDS. 6 float4/chunk direct from global (L2-resident),
//       software-pipelined one chunk ahead in registers.
//     - vmcnt ledger per iter: [issue 6 pos(c+1)] [VALU on pos(c)]
//       [vmcnt(6): drains 4 DMA(c), keeps pos(c+1)] [ds_read W + 8 MFMA]
//       [issue 4 DMA(c+1)]. sched_barrier pins the pos-issue region.
//     - merge tree + epilogue verbatim R7 (scratch overlays Wpriv after a
//       full drain + the kernel's ONLY barriers).

typedef float f32x4 __attribute__((ext_vector_type(4)));
typedef __bf16 bf16x8 __attribute__((ext_vector_type(8)));

union BF8 { bf16x8 v; uint4 u; };

#define N_PTS 4096
#define FEATD 64
#define BK 256
#define NCH (N_PTS / BK)

// ---- pre-pass: W fp32 [64][4096] -> bf16 granule-major Wbt[512][64][8] ----
// uint4 slot (G*64 + f) holds W[f][G*8 .. G*8+7] as bf16.
__global__ void wconv_kernel(const float* __restrict__ W,
                             unsigned short* __restrict__ Wbt) {
  int gid = blockIdx.x * blockDim.x + threadIdx.x;  // 32768 = 64 f * 512 G
  int f = gid >> 9, m8 = gid & 511;
  const float4* src = (const float4*)(W + (size_t)f * N_PTS + m8 * 8);
  float4 a = src[0], b = src[1];
  BF8 o;
  o.v[0] = (__bf16)a.x; o.v[1] = (__bf16)a.y; o.v[2] = (__bf16)a.z; o.v[3] = (__bf16)a.w;
  o.v[4] = (__bf16)b.x; o.v[5] = (__bf16)b.y; o.v[6] = (__bf16)b.z; o.v[7] = (__bf16)b.w;
  ((uint4*)Wbt)[(size_t)m8 * 64 + f] = o.u;
}

__device__ __forceinline__ void load_lds16(const void* g, void* l) {
  __builtin_amdgcn_global_load_lds(
      (const __attribute__((address_space(1))) void*)g,
      (__attribute__((address_space(3))) void*)l, 16, 0, 0);
}

// grid = 256 blocks (batch = bid>>6, rowtile = (bid&63)*64), block = 1024 thr.
// wave&1 = rowset (32 rows), wave>>1 = K-slice (granules ksl*4..+3 per chunk).
__global__ __launch_bounds__(1024, 4) void frp_kernel(
    const float* __restrict__ pos, const float* __restrict__ W,
    const float* __restrict__ bias, const float* __restrict__ gamma,
    const float* __restrict__ beta, const unsigned short* __restrict__ Wbt,
    float* __restrict__ out) {
  __shared__ uint4 Wpriv[2][16][256];  // 128 KiB: [buf][wave][i*64 + feat]

  const int tid = threadIdx.x;
  const int lane = tid & 63;
  const int wave = tid >> 6;
  const int rs  = wave & 1;        // rowset: rows rs*32 .. rs*32+31
  const int ksl = wave >> 1;       // 0..7: k-slice (granules ksl*4..ksl*4+3)
  const int fx = lane & 15;
  const int q = lane >> 4;

  const int batch = blockIdx.x >> 6;
  const int nb = (blockIdx.x & 63) * 64;
  const float* posB = pos + (size_t)batch * N_PTS * 3;
  const float4* p4 = (const float4*)posB;

  // this lane's two A-rows (A-frag row = lane&15), direct global (once)
  const int nrow0 = nb + rs * 32 + fx;
  const float px0 = posB[nrow0 * 3 + 0],        py0 = posB[nrow0 * 3 + 1],        pz0 = posB[nrow0 * 3 + 2];
  const float px1 = posB[(nrow0 + 16) * 3 + 0], py1 = posB[(nrow0 + 16) * 3 + 1], pz1 = posB[(nrow0 + 16) * 3 + 2];

  const bool useWb = (Wbt != nullptr);
  const int g8 = ksl * 4 + q;  // this lane's granule within a chunk

  // DMA this wave's chunk-0 W slice into its private region.
  auto stageW = [&](int c, int b) {
#pragma unroll
    for (int i = 0; i < 4; ++i)
      load_lds16(Wbt + ((size_t)(c * 2048 + (ksl * 4 + i) * 64 + lane)) * 8,
                 &Wpriv[b][wave][i * 64 + lane]);
  };

  f32x4 acc[2][4];
#pragma unroll
  for (int a = 0; a < 2; ++a)
#pragma unroll
    for (int t = 0; t < 4; ++t) acc[a][t] = (f32x4){0.f, 0.f, 0.f, 0.f};

  // prologue: issue pos(0) then DMA(0). No barrier -- everything wave-private.
  float4 f0, f1, f2, f3, f4, f5;
  {
    const int G = g8;  // chunk 0
    f0 = p4[G * 6 + 0]; f1 = p4[G * 6 + 1]; f2 = p4[G * 6 + 2];
    f3 = p4[G * 6 + 3]; f4 = p4[G * 6 + 4]; f5 = p4[G * 6 + 5];
  }
  if (useWb) stageW(0, 0);

#pragma unroll 2
  for (int c = 0; c < NCH; ++c) {
    // ---- issue pos(c+1) (6 vmem); pinned above the VALU block ----
    float4 n0, n1, n2, n3, n4, n5;
    if (c + 1 < NCH) {
      const int Gn = (c + 1) * 32 + g8;
      n0 = p4[Gn * 6 + 0]; n1 = p4[Gn * 6 + 1]; n2 = p4[Gn * 6 + 2];
      n3 = p4[Gn * 6 + 3]; n4 = p4[Gn * 6 + 4]; n5 = p4[Gn * 6 + 5];
    }
    __builtin_amdgcn_sched_barrier(0);  // pin the 6 pos issues (exact vmcnt ledger)

    // ---- distance VALU on pos(c) regs (compiler waits vmcnt(10) for these) ----
    f32x4 xa = (f32x4){f0.x, f0.w, f1.z, f2.y};
    f32x4 xb = (f32x4){f3.x, f3.w, f4.z, f5.y};
    f32x4 ya = (f32x4){f0.y, f1.x, f1.w, f2.z};
    f32x4 yb = (f32x4){f3.y, f4.x, f4.w, f5.z};
    f32x4 za = (f32x4){f0.z, f1.y, f2.x, f2.w};
    f32x4 zb = (f32x4){f3.z, f4.y, f5.x, f5.w};

    bf16x8 af0, af1;
    {
      f32x4 dx = xa - px0, dy = ya - py0, dz = za - pz0;
      f32x4 sq = dx * dx + dy * dy + dz * dz;
#pragma unroll
      for (int j = 0; j < 4; ++j) af0[j] = (__bf16)__builtin_amdgcn_sqrtf(sq[j]);
      dx = xb - px0; dy = yb - py0; dz = zb - pz0;
      sq = dx * dx + dy * dy + dz * dz;
#pragma unroll
      for (int j = 0; j < 4; ++j) af0[4 + j] = (__bf16)__builtin_amdgcn_sqrtf(sq[j]);
      dx = xa - px1; dy = ya - py1; dz = za - pz1;
      sq = dx * dx + dy * dy + dz * dz;
#pragma unroll
      for (int j = 0; j < 4; ++j) af1[j] = (__bf16)__builtin_amdgcn_sqrtf(sq[j]);
      dx = xb - px1; dy = yb - py1; dz = zb - pz1;
      sq = dx * dx + dy * dy + dz * dz;
#pragma unroll
      for (int j = 0; j < 4; ++j) af1[4 + j] = (__bf16)__builtin_amdgcn_sqrtf(sq[j]);
    }

    if (useWb) {
      // wave-local wait. Outstanding: DMA(c)=4 oldest + pos(c+1)=6 newest.
      // vmcnt(6) completes DMA(c), keeps pos(c+1) in flight. Tail: drain.
      if (c < NCH - 1) asm volatile("s_waitcnt vmcnt(6)" ::: "memory");
      else             asm volatile("s_waitcnt vmcnt(0)" ::: "memory");
      __builtin_amdgcn_sched_barrier(0);  // no ds_read/MFMA above the wait

      const uint4* Wl = &Wpriv[c & 1][wave][0];
#pragma unroll
      for (int t = 0; t < 4; ++t) {
        BF8 bw;
        bw.u = Wl[q * 64 + t * 16 + fx];  // one read, two MFMAs
        acc[0][t] = __builtin_amdgcn_mfma_f32_16x16x32_bf16(af0, bw.v, acc[0][t], 0, 0, 0);
        acc[1][t] = __builtin_amdgcn_mfma_f32_16x16x32_bf16(af1, bw.v, acc[1][t], 0, 0, 0);
      }
      // issue DMA(c+1) after compute (lands during next iter's VALU)
      if (c + 1 < NCH) stageW(c + 1, (c + 1) & 1);
    } else {
      // fallback: W direct from global fp32 + convert (no LDS, no DMA)
#pragma unroll
      for (int t = 0; t < 4; ++t) {
        const int G = c * 32 + g8;
        const float4* src = (const float4*)(W + (size_t)(t * 16 + fx) * N_PTS + G * 8);
        float4 a4 = src[0], b4 = src[1];
        BF8 bw;
        bw.v[0] = (__bf16)a4.x; bw.v[1] = (__bf16)a4.y; bw.v[2] = (__bf16)a4.z; bw.v[3] = (__bf16)a4.w;
        bw.v[4] = (__bf16)b4.x; bw.v[5] = (__bf16)b4.y; bw.v[6] = (__bf16)b4.z; bw.v[7] = (__bf16)b4.w;
        acc[0][t] = __builtin_amdgcn_mfma_f32_16x16x32_bf16(af0, bw.v, acc[0][t], 0, 0, 0);
        acc[1][t] = __builtin_amdgcn_mfma_f32_16x16x32_bf16(af1, bw.v, acc[1][t], 0, 0, 0);
      }
    }

    // rotate pos pipeline (unroll-2 lets the compiler rename these away)
    if (c + 1 < NCH) { f0 = n0; f1 = n1; f2 = n2; f3 = n3; f4 = n4; f5 = n5; }
  }

  // ---- 8-way K-merge via LDS (reuse Wpriv; needs 64 of the 128 KiB) ----
  f32x4* mbv = (f32x4*)Wpriv;
  // All own DMAs drained (tail vmcnt(0)); first barrier of the kernel.
  __syncthreads();
  if (ksl >= 4) {
    int w = (ksl - 4) * 2 + rs;
#pragma unroll
    for (int a = 0; a < 2; ++a)
#pragma unroll
      for (int t = 0; t < 4; ++t)
        mbv[w * 512 + (a * 4 + t) * 64 + lane] = acc[a][t];
  }
  __syncthreads();
  if (ksl < 4) {
    int w = ksl * 2 + rs;
#pragma unroll
    for (int a = 0; a < 2; ++a)
#pragma unroll
      for (int t = 0; t < 4; ++t)
        acc[a][t] += mbv[w * 512 + (a * 4 + t) * 64 + lane];
  }
  __syncthreads();
  if (ksl >= 1 && ksl < 4) {
    int w = (ksl - 1) * 2 + rs;
#pragma unroll
    for (int a = 0; a < 2; ++a)
#pragma unroll
      for (int t = 0; t < 4; ++t)
        mbv[w * 512 + (a * 4 + t) * 64 + lane] = acc[a][t];
  }
  __syncthreads();
  if (ksl == 0) {
#pragma unroll
    for (int s = 0; s < 3; ++s)
#pragma unroll
      for (int a = 0; a < 2; ++a)
#pragma unroll
        for (int t = 0; t < 4; ++t)
          acc[a][t] += mbv[(s * 2 + rs) * 512 + (a * 4 + t) * 64 + lane];

    // epilogue: bias + LayerNorm(64) + SiLU. C/D layout: col=lane&15, row=q*4+r.
    float bb[4], gg[4], be[4];
#pragma unroll
    for (int t = 0; t < 4; ++t) {
      bb[t] = bias[t * 16 + fx];
      gg[t] = gamma[t * 16 + fx];
      be[t] = beta[t * 16 + fx];
    }
    float* outB = out + ((size_t)batch * N_PTS + nb + rs * 32) * FEATD;
#pragma unroll
    for (int a = 0; a < 2; ++a) {
#pragma unroll
      for (int r = 0; r < 4; ++r) {
        float x[4], d[4];
#pragma unroll
        for (int t = 0; t < 4; ++t) x[t] = acc[a][t][r] + bb[t];
        float s = x[0] + x[1] + x[2] + x[3];
        s += __shfl_xor(s, 1); s += __shfl_xor(s, 2);
        s += __shfl_xor(s, 4); s += __shfl_xor(s, 8);
        float mu = s * (1.f / 64.f);
        float v = 0.f;
#pragma unroll
        for (int t = 0; t < 4; ++t) { d[t] = x[t] - mu; v += d[t] * d[t]; }
        v += __shfl_xor(v, 1); v += __shfl_xor(v, 2);
        v += __shfl_xor(v, 4); v += __shfl_xor(v, 8);
        float rstd = __builtin_amdgcn_rsqf(v * (1.f / 64.f) + 1e-5f);
        float* orow = outB + (a * 16 + q * 4 + r) * FEATD;
#pragma unroll
        for (int t = 0; t < 4; ++t) {
          float xn = d[t] * rstd * gg[t] + be[t];
          float y = xn * (1.f / (1.f + __expf(-xn)));  // SiLU
          orow[t * 16 + fx] = y;
        }
      }
    }
  }
}

extern "C" void kernel_launch(void* const* d_in, const int* in_sizes, int n_in,
                              void* d_out, int out_size, void* d_ws, size_t ws_size,
                              hipStream_t stream) {
  const float* pos   = (const float*)d_in[0];  // (4,4096,3)
  const float* W     = (const float*)d_in[1];  // (64,4096)
  const float* bias  = (const float*)d_in[2];  // (64,)
  const float* gamma = (const float*)d_in[3];  // (64,)
  const float* beta  = (const float*)d_in[4];  // (64,)
  float* out = (float*)d_out;                  // (4,4096,64)

  const size_t wb_bytes = (size_t)FEATD * N_PTS * sizeof(unsigned short);  // 512 KiB
  int use_ws = (d_ws != nullptr && ws_size >= wb_bytes);
  unsigned short* Wbt = use_ws ? (unsigned short*)d_ws : nullptr;

  if (use_ws) {
    wconv_kernel<<<dim3((FEATD * N_PTS / 8) / 256), dim3(256), 0, stream>>>(W, Wbt);
  }
  frp_kernel<<<dim3(256), dim3(1024), 0, stream>>>(pos, W, bias, gamma, beta, Wbt, out);
}

// Round 7
// 90.685 us; speedup vs baseline: 1.7216x; 1.7216x over previous
//
#include <hip/hip_runtime.h>

// FeatureWithRelativePosition: fused pairwise-dist -> Linear(4096->64) -> LN -> SiLU
// BS=4, N=4096, FEAT=64. fp32 in/out, bf16 MFMA inner product, fp32 accumulate.
//
// R10: zero in-loop barriers, ALL hazards wave-local (fixes R9's rs-pair race:
//      "idempotent" shared DMA wasn't idempotent across chunk skew).
//      - 16 waves/block (1024 thr, 4 waves/SIMD). wave = (rs, ksl) as R4.
//      - W: wave-PRIVATE SINGLE-buffered 4 KiB slice (Wpriv[16][256], 64 KiB).
//        Per iter: dist VALU -> vmcnt(0) [own 4 DMAs only] -> 4x ds_read W ->
//        lgkmcnt(0) [buffer free] -> issue DMA(c+1) into same buffer -> 8 MFMA.
//        No cross-wave sharing, no pipeline regs (R8 spill), no skew hazard.
//      - pos staged once in LDS (48 KiB), read-only afterward.
//      - ZERO barriers between prologue and K-merge; waves free-run so the
//        LDS pipe stays continuously busy (R4/R7: per-chunk all-wave
//        convergence left it at ~50%).

typedef float f32x4 __attribute__((ext_vector_type(4)));
typedef __bf16 bf16x8 __attribute__((ext_vector_type(8)));

union BF8 { bf16x8 v; uint4 u; };

#define N_PTS 4096
#define FEATD 64
#define BK 256
#define NCH (N_PTS / BK)

// ---- pre-pass: W fp32 [64][4096] -> bf16 granule-major Wbt[512][64][8] ----
// uint4 slot (G*64 + f) holds W[f][G*8 .. G*8+7] as bf16.
__global__ void wconv_kernel(const float* __restrict__ W,
                             unsigned short* __restrict__ Wbt) {
  int gid = blockIdx.x * blockDim.x + threadIdx.x;  // 32768 = 64 f * 512 G
  int f = gid >> 9, m8 = gid & 511;
  const float4* src = (const float4*)(W + (size_t)f * N_PTS + m8 * 8);
  float4 a = src[0], b = src[1];
  BF8 o;
  o.v[0] = (__bf16)a.x; o.v[1] = (__bf16)a.y; o.v[2] = (__bf16)a.z; o.v[3] = (__bf16)a.w;
  o.v[4] = (__bf16)b.x; o.v[5] = (__bf16)b.y; o.v[6] = (__bf16)b.z; o.v[7] = (__bf16)b.w;
  ((uint4*)Wbt)[(size_t)m8 * 64 + f] = o.u;
}

__device__ __forceinline__ void load_lds16(const void* g, void* l) {
  __builtin_amdgcn_global_load_lds(
      (const __attribute__((address_space(1))) void*)g,
      (__attribute__((address_space(3))) void*)l, 16, 0, 0);
}

// grid = 256 blocks (batch = bid>>6, rowtile = (bid&63)*64), block = 1024 thr.
// wave&1 = rowset (32 rows), wave>>1 = K-slice (granules ksl*4..+3 per chunk).
__global__ __launch_bounds__(1024, 4) void frp_kernel(
    const float* __restrict__ pos, const float* __restrict__ W,
    const float* __restrict__ bias, const float* __restrict__ gamma,
    const float* __restrict__ beta, const unsigned short* __restrict__ Wbt,
    float* __restrict__ out) {
  __shared__ uint4 Wpriv[16][256];           // 64 KiB: [wave][i*64 + feat]
  __shared__ __align__(16) float Px[N_PTS];  // 16 KiB each, SoA
  __shared__ __align__(16) float Py[N_PTS];
  __shared__ __align__(16) float Pz[N_PTS];

  const int tid = threadIdx.x;
  const int lane = tid & 63;
  const int wave = tid >> 6;
  const int rs  = wave & 1;        // rowset: rows rs*32 .. rs*32+31
  const int ksl = wave >> 1;       // 0..7: k-slice (granules ksl*4..ksl*4+3)
  const int fx = lane & 15;
  const int q = lane >> 4;

  const int batch = blockIdx.x >> 6;
  const int nb = (blockIdx.x & 63) * 64;
  const float* posB = pos + (size_t)batch * N_PTS * 3;

  // ---- stage ALL positions SoA (once). 1024 thr x 4 pts, float4 in/out. ----
  {
    const float4* p4 = (const float4*)posB;
    float4 f0 = p4[tid * 3 + 0];
    float4 f1 = p4[tid * 3 + 1];
    float4 f2 = p4[tid * 3 + 2];
    ((float4*)Px)[tid] = make_float4(f0.x, f0.w, f1.z, f2.y);
    ((float4*)Py)[tid] = make_float4(f0.y, f1.x, f1.w, f2.z);
    ((float4*)Pz)[tid] = make_float4(f0.z, f1.y, f2.x, f2.w);
  }

  const bool useWb = (Wbt != nullptr);

  // ---- wave-private W slice staging (4 granules = 4 KiB), single buffer ----
  auto stageW = [&](int c) {
    if (useWb) {
#pragma unroll
      for (int i = 0; i < 4; ++i)
        load_lds16(Wbt + ((size_t)((c * 32 + ksl * 4 + i) * 64 + lane)) * 8,
                   &Wpriv[wave][i * 64 + lane]);
    } else {
      // fallback: inline fp32->bf16 conversion into own region (wave-local)
#pragma unroll
      for (int i = 0; i < 4; ++i) {
        const float4* src =
            (const float4*)(W + (size_t)lane * N_PTS + c * BK + (ksl * 4 + i) * 8);
        float4 a4 = src[0], b4 = src[1];
        BF8 o;
        o.v[0] = (__bf16)a4.x; o.v[1] = (__bf16)a4.y; o.v[2] = (__bf16)a4.z; o.v[3] = (__bf16)a4.w;
        o.v[4] = (__bf16)b4.x; o.v[5] = (__bf16)b4.y; o.v[6] = (__bf16)b4.z; o.v[7] = (__bf16)b4.w;
        Wpriv[wave][i * 64 + lane] = o.u;
      }
    }
  };

  f32x4 acc[2][4];
#pragma unroll
  for (int a = 0; a < 2; ++a)
#pragma unroll
    for (int t = 0; t < 4; ++t) acc[a][t] = (f32x4){0.f, 0.f, 0.f, 0.f};

  stageW(0);
  __syncthreads();   // pos staged (cross-wave, read-only after). Also drains
                     // DMA(0). LAST barrier until the K-merge.

  // this lane's two A-rows (A-frag row = lane&15); read from LDS (broadcast)
  const int nrow0 = nb + rs * 32 + fx;
  const float px0 = Px[nrow0],      py0 = Py[nrow0],      pz0 = Pz[nrow0];
  const float px1 = Px[nrow0 + 16], py1 = Py[nrow0 + 16], pz1 = Pz[nrow0 + 16];

  const int g8 = ksl * 4 + q;          // this lane's granule (8 pts) within chunk

  for (int c = 0; c < NCH; ++c) {
    // ---- distance VALU on LDS pos (W DMA for this chunk still in flight) ----
    const int m4 = c * 64 + g8 * 2;               // f32x4 index into SoA arrays
    f32x4 xa = ((const f32x4*)Px)[m4], xb = ((const f32x4*)Px)[m4 + 1];
    f32x4 ya = ((const f32x4*)Py)[m4], yb = ((const f32x4*)Py)[m4 + 1];
    f32x4 za = ((const f32x4*)Pz)[m4], zb = ((const f32x4*)Pz)[m4 + 1];

    bf16x8 af0, af1;
    {
      f32x4 dx = xa - px0, dy = ya - py0, dz = za - pz0;
      f32x4 sq = dx * dx + dy * dy + dz * dz;
#pragma unroll
      for (int j = 0; j < 4; ++j) af0[j] = (__bf16)__builtin_amdgcn_sqrtf(sq[j]);
      dx = xb - px0; dy = yb - py0; dz = zb - pz0;
      sq = dx * dx + dy * dy + dz * dz;
#pragma unroll
      for (int j = 0; j < 4; ++j) af0[4 + j] = (__bf16)__builtin_amdgcn_sqrtf(sq[j]);
      dx = xa - px1; dy = ya - py1; dz = za - pz1;
      sq = dx * dx + dy * dy + dz * dz;
#pragma unroll
      for (int j = 0; j < 4; ++j) af1[j] = (__bf16)__builtin_amdgcn_sqrtf(sq[j]);
      dx = xb - px1; dy = yb - py1; dz = zb - pz1;
      sq = dx * dx + dy * dy + dz * dz;
#pragma unroll
      for (int j = 0; j < 4; ++j) af1[4 + j] = (__bf16)__builtin_amdgcn_sqrtf(sq[j]);
    }

    // ---- own DMA(c) landed? (only our 4 DMAs are ever outstanding) ----
    if (useWb) asm volatile("s_waitcnt vmcnt(0)" ::: "memory");
    __builtin_amdgcn_sched_barrier(0);   // nothing (esp. ds_read W) above the wait

    // ---- consume W(c): 4 reads -> regs; then buffer is free ----
    BF8 bw[4];
#pragma unroll
    for (int t = 0; t < 4; ++t)
      bw[t].u = Wpriv[wave][q * 64 + t * 16 + fx];  // one read, two MFMAs
    asm volatile("s_waitcnt lgkmcnt(0)" ::: "memory");
    __builtin_amdgcn_sched_barrier(0);   // bw in regs; LDS slice reusable

    // ---- refill own buffer for chunk c+1 (lands during next iter's VALU) ----
    if (c + 1 < NCH) stageW(c + 1);
    __builtin_amdgcn_sched_barrier(0);   // keep DMA issue above the MFMAs

#pragma unroll
    for (int t = 0; t < 4; ++t) {
      acc[0][t] = __builtin_amdgcn_mfma_f32_16x16x32_bf16(af0, bw[t].v, acc[0][t], 0, 0, 0);
      acc[1][t] = __builtin_amdgcn_mfma_f32_16x16x32_bf16(af1, bw[t].v, acc[1][t], 0, 0, 0);
    }
    // no barrier: Wpriv[wave] is wave-private; pos is read-only.
  }

  // ---- 8-way K-merge via LDS (overlay Wpriv: 4096 f32x4 = 64 KiB) ----
  f32x4* mbv = (f32x4*)Wpriv;
  __syncthreads();  // first barrier since prologue; every wave's DMAs drained
                    // (vmcnt(0) ran in its last iteration, no issue after it)
  if (ksl >= 4) {
    int w = (ksl - 4) * 2 + rs;
#pragma unroll
    for (int a = 0; a < 2; ++a)
#pragma unroll
      for (int t = 0; t < 4; ++t)
        mbv[w * 512 + (a * 4 + t) * 64 + lane] = acc[a][t];
  }
  __syncthreads();
  if (ksl < 4) {
    int w = ksl * 2 + rs;
#pragma unroll
    for (int a = 0; a < 2; ++a)
#pragma unroll
      for (int t = 0; t < 4; ++t)
        acc[a][t] += mbv[w * 512 + (a * 4 + t) * 64 + lane];
  }
  __syncthreads();
  if (ksl >= 1 && ksl < 4) {
    int w = (ksl - 1) * 2 + rs;
#pragma unroll
    for (int a = 0; a < 2; ++a)
#pragma unroll
      for (int t = 0; t < 4; ++t)
        mbv[w * 512 + (a * 4 + t) * 64 + lane] = acc[a][t];
  }
  __syncthreads();
  if (ksl == 0) {
#pragma unroll
    for (int s = 0; s < 3; ++s)
#pragma unroll
      for (int a = 0; a < 2; ++a)
#pragma unroll
        for (int t = 0; t < 4; ++t)
          acc[a][t] += mbv[(s * 2 + rs) * 512 + (a * 4 + t) * 64 + lane];

    // epilogue: bias + LayerNorm(64) + SiLU. C/D layout: col=lane&15, row=q*4+r.
    float bb[4], gg[4], be[4];
#pragma unroll
    for (int t = 0; t < 4; ++t) {
      bb[t] = bias[t * 16 + fx];
      gg[t] = gamma[t * 16 + fx];
      be[t] = beta[t * 16 + fx];
    }
    float* outB = out + ((size_t)batch * N_PTS + nb + rs * 32) * FEATD;
#pragma unroll
    for (int a = 0; a < 2; ++a) {
#pragma unroll
      for (int r = 0; r < 4; ++r) {
        float x[4], d[4];
#pragma unroll
        for (int t = 0; t < 4; ++t) x[t] = acc[a][t][r] + bb[t];
        float s = x[0] + x[1] + x[2] + x[3];
        s += __shfl_xor(s, 1); s += __shfl_xor(s, 2);
        s += __shfl_xor(s, 4); s += __shfl_xor(s, 8);
        float mu = s * (1.f / 64.f);
        float v = 0.f;
#pragma unroll
        for (int t = 0; t < 4; ++t) { d[t] = x[t] - mu; v += d[t] * d[t]; }
        v += __shfl_xor(v, 1); v += __shfl_xor(v, 2);
        v += __shfl_xor(v, 4); v += __shfl_xor(v, 8);
        float rstd = __builtin_amdgcn_rsqf(v * (1.f / 64.f) + 1e-5f);
        float* orow = outB + (a * 16 + q * 4 + r) * FEATD;
#pragma unroll
        for (int t = 0; t < 4; ++t) {
          float xn = d[t] * rstd * gg[t] + be[t];
          float y = xn * (1.f / (1.f + __expf(-xn)));  // SiLU
          orow[t * 16 + fx] = y;
        }
      }
    }
  }
}

extern "C" void kernel_launch(void* const* d_in, const int* in_sizes, int n_in,
                              void* d_out, int out_size, void* d_ws, size_t ws_size,
                              hipStream_t stream) {
  const float* pos   = (const float*)d_in[0];  // (4,4096,3)
  const float* W     = (const float*)d_in[1];  // (64,4096)
  const float* bias  = (const float*)d_in[2];  // (64,)
  const float* gamma = (const float*)d_in[3];  // (64,)
  const float* beta  = (const float*)d_in[4];  // (64,)
  float* out = (float*)d_out;                  // (4,4096,64)

  const size_t wb_bytes = (size_t)FEATD * N_PTS * sizeof(unsigned short);  // 512 KiB
  int use_ws = (d_ws != nullptr && ws_size >= wb_bytes);
  unsigned short* Wbt = use_ws ? (unsigned short*)d_ws : nullptr;

  if (use_ws) {
    wconv_kernel<<<dim3((FEATD * N_PTS / 8) / 256), dim3(256), 0, stream>>>(W, Wbt);
  }
  frp_kernel<<<dim3(256), dim3(1024), 0, stream>>>(pos, W, bias, gamma, beta, Wbt, out);
}